// Round 6
// baseline (236.609 us; speedup 1.0000x reference)
//
#include <hip/hip_runtime.h>
#include <hip/hip_bf16.h>

#define T_TOKENS 65536
#define EMBED 256
#define DOWN 64
#define NE 10
#define NPAIR 100          // ordered (e0,e1) buckets, e0=top1
#define MAXQ 1280          // >= 1024 + 99 tiles worst case
#define NGATE 256          // gating blocks (T_TOKENS/256)
#define NPACK 160          // pack role blocks
#define NEXP 1123          // expert grid: worst-case tiles 1024 + 99

typedef __attribute__((ext_vector_type(8))) short short8;   // 8 bf16 (MFMA A/B frag)
typedef __attribute__((ext_vector_type(4))) float f32x4;    // MFMA C/D frag

__device__ inline unsigned short f2bf(float f) {            // RNE float->bf16
    unsigned u = __builtin_bit_cast(unsigned, f);
    u += 0x7fff + ((u >> 16) & 1);
    return (unsigned short)(u >> 16);
}
__device__ inline float bf2f(unsigned short h) {
    unsigned u = ((unsigned)h) << 16;
    return __builtin_bit_cast(float, u);
}

// ---------------- Kernel 1 (fused, fence-free): gating blocks [0,256) + pack blocks [256,416) ----
// Roles independent; kernel boundary before expert provides ordering. No fences/counters
// (round-4 lesson: device fence per block -> per-block L2 writeback -> +117us).
// Gating FMA order IDENTICAL to prior rounds -- do not reorder: near-tie top-k.
__global__ __launch_bounds__(256) void gate_pack_kernel(
    const float* __restrict__ x, const float* __restrict__ wg,
    const float* __restrict__ w1, const float* __restrict__ w2,
    unsigned short* __restrict__ w1ph, unsigned short* __restrict__ w1pl,
    unsigned short* __restrict__ w2ph, unsigned short* __restrict__ w2pl,
    int* __restrict__ pcount, float* __restrict__ importance,
    int* __restrict__ btok, float* __restrict__ bg0)
{
    int tid = threadIdx.x;

    if (blockIdx.x >= NGATE) {                 // ---- pack role ----
        int gid = (blockIdx.x - NGATE) * 256 + tid;
        int lane = gid & 63;
        int fid = gid >> 6;
        int n16 = lane & 15;
        int kbase = ((lane >> 4) & 3) * 8;
        if (fid < 320) {            // w1: fid = (e*4 + ct)*8 + kb
            int kb = fid & 7, ect = fid >> 3;
            int ct = ect & 3, e = ect >> 2;
            int n = ct * 16 + n16;
            int k0 = kb * 32 + kbase;
#pragma unroll
            for (int j = 0; j < 8; ++j) {
                float v = w1[((size_t)e * EMBED + k0 + j) * DOWN + n];
                unsigned short h = f2bf(v);
                w1ph[(size_t)fid * 512 + lane * 8 + j] = h;
                w1pl[(size_t)fid * 512 + lane * 8 + j] = f2bf(v - bf2f(h));
            }
        } else if (fid < 640) {     // w2: f2 = (e*16 + ct)*2 + kb
            int f2 = fid - 320;
            int kb = f2 & 1, ect = f2 >> 1;
            int ct = ect & 15, e = ect >> 4;
            int n = ct * 16 + n16;
            int k0 = kb * 32 + kbase;
#pragma unroll
            for (int j = 0; j < 8; ++j) {
                float v = w2[((size_t)e * DOWN + k0 + j) * EMBED + n];
                unsigned short h = f2bf(v);
                w2ph[(size_t)f2 * 512 + lane * 8 + j] = h;
                w2pl[(size_t)f2 * 512 + lane * 8 + j] = f2bf(v - bf2f(h));
            }
        }
        return;
    }

    // ---- gating role (body identical to round-3/5) ----
    __shared__ float Xs[2][256 * 33];    // stride 33: compute reads (tid+c)%32 conflict-free
    __shared__ int lcount[NPAIR];
    __shared__ int gbase[NPAIR];
    __shared__ float limp[16];
    if (tid < NPAIR) lcount[tid] = 0;
    if (tid < 16) limp[tid] = 0.f;

    int tokbase = blockIdx.x * 256;
    const float4* x4 = (const float4*)x;
    int rbase = tid >> 3, c4 = tid & 7;   // 8 rows x 8 float4: 128B segments per row

    float4 pre0[8], pre1[8];
#pragma unroll
    for (int i = 0; i < 8; ++i)
        pre0[i] = x4[(size_t)(tokbase + i * 32 + rbase) * 64 + c4];
#pragma unroll
    for (int i = 0; i < 8; ++i)
        pre1[i] = x4[(size_t)(tokbase + i * 32 + rbase) * 64 + 8 + c4];

    float acc[NE];
#pragma unroll
    for (int e = 0; e < NE; e++) acc[e] = 0.f;

    for (int cp = 0; cp < 4; ++cp) {
        {   // even chunk cc = 2*cp -> buffer 0, regs pre0
            float* buf = Xs[0];
#pragma unroll
            for (int i = 0; i < 8; ++i) {
                float* d = &buf[(i * 32 + rbase) * 33 + c4 * 4];
                d[0] = pre0[i].x; d[1] = pre0[i].y; d[2] = pre0[i].z; d[3] = pre0[i].w;
            }
            if (cp < 3) {
#pragma unroll
                for (int i = 0; i < 8; ++i)
                    pre0[i] = x4[(size_t)(tokbase + i * 32 + rbase) * 64 + (2 * cp + 2) * 8 + c4];
            }
            __syncthreads();   // single barrier/chunk: buffer alternation protects reuse
            const float* wgc = wg + (2 * cp) * 32 * NE;   // wave-uniform -> scalar loads
#pragma unroll
            for (int c = 0; c < 32; ++c) {
                float xv = buf[tid * 33 + c];
#pragma unroll
                for (int e = 0; e < NE; ++e)
                    acc[e] = fmaf(xv, wgc[c * NE + e], acc[e]);
            }
        }
        {   // odd chunk cc = 2*cp+1 -> buffer 1, regs pre1
            float* buf = Xs[1];
#pragma unroll
            for (int i = 0; i < 8; ++i) {
                float* d = &buf[(i * 32 + rbase) * 33 + c4 * 4];
                d[0] = pre1[i].x; d[1] = pre1[i].y; d[2] = pre1[i].z; d[3] = pre1[i].w;
            }
            if (cp < 3) {
#pragma unroll
                for (int i = 0; i < 8; ++i)
                    pre1[i] = x4[(size_t)(tokbase + i * 32 + rbase) * 64 + (2 * cp + 3) * 8 + c4];
            }
            __syncthreads();
            const float* wgc = wg + (2 * cp + 1) * 32 * NE;
#pragma unroll
            for (int c = 0; c < 32; ++c) {
                float xv = buf[tid * 33 + c];
#pragma unroll
                for (int e = 0; e < NE; ++e)
                    acc[e] = fmaf(xv, wgc[c * NE + e], acc[e]);
            }
        }
    }

    // top-2 (first occurrence wins ties, matches lax.top_k)
    float l0 = -INFINITY, l1 = -INFINITY;
    int i0 = 0, i1 = 0;
#pragma unroll
    for (int e = 0; e < NE; e++) {
        float v = acc[e];
        if (v > l0) { l1 = l0; i1 = i0; l0 = v; i0 = e; }
        else if (v > l1) { l1 = v; i1 = e; }
    }
    float ex = __expf(l1 - l0);
    float g0 = 1.f / (1.f + ex);

    int p = i0 * NE + i1;
    int lp = atomicAdd(&lcount[p], 1);
    atomicAdd(&limp[i0], g0);
    atomicAdd(&limp[i1], 1.f - g0);
    __syncthreads();
    if (tid < NPAIR) {
        int c = lcount[tid];
        gbase[tid] = c ? atomicAdd(&pcount[tid], c) : 0;
    }
    if (tid < NE) atomicAdd(&importance[tid], limp[tid]);
    __syncthreads();
    int pos = gbase[p] + lp;
    btok[p * T_TOKENS + pos] = tokbase + tid;
    bg0[p * T_TOKENS + pos] = g0;
}

// ---------------- Kernel 2: build tile work-queue (parallel scan) -------------------------------
__global__ __launch_bounds__(128) void queue_kernel(const int* __restrict__ pcount,
                             int* __restrict__ qp, int* __restrict__ qs, int* __restrict__ nq)
{
    __shared__ int sc[2][128];
    int tid = threadIdx.x;
    int c = (tid < NPAIR) ? pcount[tid] : 0;
    int t = (c + 63) >> 6;
    sc[0][tid] = t;
    __syncthreads();
    int cur = 0;
#pragma unroll
    for (int o = 1; o < 128; o <<= 1) {    // Hillis-Steele inclusive scan
        int v = sc[cur][tid] + ((tid >= o) ? sc[cur][tid - o] : 0);
        sc[cur ^ 1][tid] = v;
        __syncthreads();
        cur ^= 1;
    }
    int incl = sc[cur][tid];
    int excl = incl - t;
    if (tid == 127) *nq = incl;            // tids >= NPAIR contribute 0
    for (int i = 0; i < t; ++i) { qp[excl + i] = tid; qs[excl + i] = i * 64; }
}

// ---------------- Kernel 3: fused pair-FFN -------------------------------------------------------
// Round-6: LDS squeezed to EXACTLY 32 KB -> 5 blocks/CU (was 33792 -> 4) -> 1280 resident slots
// >= 1123 tiles: single residency round, tail eliminated. Changes vs the 75.5us round-5 body:
// (a) X staging pad removed (XROW 72->64); bank conflicts handled by XOR swizzle idx^=(row&7)<<3
//     (row stride 128B == 32 banks exactly, XOR spreads 16 lanes over 8 16B slots -> 2-way = free);
// (b) toks/gv0s/gv1s/kdw LDS dropped: btok/bg0 re-read from global (64 contiguous ints/floats per
//     tile, L2-hot); KD reduced via one atomicAdd per wave. Compute order of every FLOP unchanged.
__global__ __launch_bounds__(256, 3) void expert_kernel(
    const float* __restrict__ x,
    const unsigned short* __restrict__ w1ph, const unsigned short* __restrict__ w1pl,
    const unsigned short* __restrict__ w2ph, const unsigned short* __restrict__ w2pl,
    const float* __restrict__ b1, const float* __restrict__ b2,
    const int* __restrict__ pcount, const int* __restrict__ qp, const int* __restrict__ qs,
    const int* __restrict__ nq,
    const int* __restrict__ btok, const float* __restrict__ bg0,
    float* __restrict__ out, float* __restrict__ kdpart)
{
    int bid = blockIdx.x;
    if (bid >= *nq) return;
    int p = qp[bid], s = qs[bid];
    int e0 = p / NE, e1 = p - e0 * NE;
    int m = min(64, pcount[p] - s);
    const int*   btokp = btok + (size_t)p * T_TOKENS + s;   // 64 contiguous ints, L2-hot
    const float* bg0p  = bg0  + (size_t)p * T_TOKENS + s;

    __shared__ __align__(16) unsigned short Hbuf[16384];   // EXACTLY 32 KB; only LDS in kernel
    // X overlay (GEMM1 staging, XOR-swizzled): Xh [64 rows x 64 shorts], Xl same, 16 KB total
    unsigned short* const Xh  = Hbuf;
    unsigned short* const Xl  = Hbuf + 4096;
    // H overlay (GEMM2 A-frags, written after X is dead): 4 x 8 KB
    unsigned short* const H0h = Hbuf;
    unsigned short* const H0l = Hbuf + 4096;
    unsigned short* const H1h = Hbuf + 8192;
    unsigned short* const H1l = Hbuf + 12288;

    int tid = threadIdx.x;
    int lane = tid & 63, wv = tid >> 6;
    int ln15 = lane & 15, quad = lane >> 4;
    int srow = tid >> 2, sc0 = (tid & 3) * 16;
    bool srow_ok = srow < m;
    int tokS = srow_ok ? btokp[srow] : 0;
    const float* xrow = x + (size_t)tokS * EMBED;

    f32x4 a10[4], a11[4];
#pragma unroll
    for (int rt = 0; rt < 4; ++rt) { a10[rt] = (f32x4){0,0,0,0}; a11[rt] = (f32x4){0,0,0,0}; }

    const unsigned short* w1h0 = w1ph + (((size_t)e0 * 4 + wv) * 8) * 512;
    const unsigned short* w1l0 = w1pl + (((size_t)e0 * 4 + wv) * 8) * 512;
    const unsigned short* w1h1 = w1ph + (((size_t)e1 * 4 + wv) * 8) * 512;
    const unsigned short* w1l1 = w1pl + (((size_t)e1 * 4 + wv) * 8) * 512;

    for (int cc = 0; cc < 4; ++cc) {                 // K chunks of 64
#pragma unroll
        for (int p4 = 0; p4 < 4; ++p4) {
            int col = sc0 + p4 * 4;
            float4 v = make_float4(0.f, 0.f, 0.f, 0.f);
            if (srow_ok) v = *(const float4*)(xrow + cc * 64 + col);
            const float* vs = (const float*)&v;
            ushort4 hv, lv;
            unsigned short* hp = (unsigned short*)&hv;
            unsigned short* lp2 = (unsigned short*)&lv;
#pragma unroll
            for (int i = 0; i < 4; ++i) {
                unsigned short h = f2bf(vs[i]);
                hp[i] = h;
                lp2[i] = f2bf(vs[i] - bf2f(h));
            }
            int sidx = (srow * 64 + col) ^ ((srow & 7) << 3);   // 16B-slot XOR swizzle
            *(ushort4*)&Xh[sidx] = hv;
            *(ushort4*)&Xl[sidx] = lv;
        }
        __syncthreads();
#pragma unroll
        for (int kb = 0; kb < 2; ++kb) {
            int kbg = cc * 2 + kb;
            short8 bh0 = *(const short8*)(w1h0 + (size_t)kbg * 512 + lane * 8);
            short8 bl0 = *(const short8*)(w1l0 + (size_t)kbg * 512 + lane * 8);
            short8 bh1 = *(const short8*)(w1h1 + (size_t)kbg * 512 + lane * 8);
            short8 bl1 = *(const short8*)(w1l1 + (size_t)kbg * 512 + lane * 8);
            int aoff = kb * 32 + quad * 8;
#pragma unroll
            for (int rt = 0; rt < 4; ++rt) {
                int row = rt * 16 + ln15;
                int aidx = (row * 64 + aoff) ^ ((row & 7) << 3);
                short8 ah = *(const short8*)&Xh[aidx];
                short8 al = *(const short8*)&Xl[aidx];
                a10[rt] = __builtin_amdgcn_mfma_f32_16x16x32_bf16(ah, bh0, a10[rt], 0, 0, 0);
                a10[rt] = __builtin_amdgcn_mfma_f32_16x16x32_bf16(ah, bl0, a10[rt], 0, 0, 0);
                a10[rt] = __builtin_amdgcn_mfma_f32_16x16x32_bf16(al, bh0, a10[rt], 0, 0, 0);
                a11[rt] = __builtin_amdgcn_mfma_f32_16x16x32_bf16(ah, bh1, a11[rt], 0, 0, 0);
                a11[rt] = __builtin_amdgcn_mfma_f32_16x16x32_bf16(ah, bl1, a11[rt], 0, 0, 0);
                a11[rt] = __builtin_amdgcn_mfma_f32_16x16x32_bf16(al, bh1, a11[rt], 0, 0, 0);
            }
        }
        __syncthreads();     // all X reads done; safe to overwrite Xh/Xl (after cc=3, Hbuf as H)
    }

    // H epilogue: bias+relu, pre-scale by gates (re-read from bg0, L2-hot), A-frag order write.
    {
        float b1v0 = b1[e0 * DOWN + wv * 16 + ln15];
        float b1v1 = b1[e1 * DOWN + wv * 16 + ln15];
        int kbH = wv >> 1;
        int laneH = (((wv & 1) * 2 + (ln15 >> 3)) * 16) + quad * 4;
        int jH = ln15 & 7;
#pragma unroll
        for (int rt = 0; rt < 4; ++rt) {
#pragma unroll
            for (int r = 0; r < 4; ++r) {
                int row = rt * 16 + quad * 4 + r;
                float g0 = (row < m) ? bg0p[row] : 0.f;
                float g1 = (row < m) ? (1.f - g0) : 0.f;
                float h0 = fmaxf(a10[rt][r] + b1v0, 0.f) * g0;
                float h1 = fmaxf(a11[rt][r] + b1v1, 0.f) * g1;
                int idx = ((rt * 2 + kbH) * 64 + laneH + r) * 8 + jH;
                unsigned short h0h = f2bf(h0);
                unsigned short h1h = f2bf(h1);
                H0h[idx] = h0h; H0l[idx] = f2bf(h0 - bf2f(h0h));
                H1h[idx] = h1h; H1l[idx] = f2bf(h1 - bf2f(h1h));
            }
        }
    }
    __syncthreads();

    // GEMM2: y = (g0 h0) w2_e0 + (g1 h1) w2_e1; epilogue adds gated biases, KD, 0.5 scale
    float b20[4], b21[4];
#pragma unroll
    for (int ci = 0; ci < 4; ++ci) {
        b20[ci] = b2[e0 * EMBED + (wv * 4 + ci) * 16 + ln15];
        b21[ci] = b2[e1 * EMBED + (wv * 4 + ci) * 16 + ln15];
    }
    float kdacc = 0.f;
#pragma unroll
    for (int rt = 0; rt < 4; ++rt) {
        short8 ah0[2], al0[2], ah1[2], al1[2];
#pragma unroll
        for (int kb = 0; kb < 2; ++kb) {
            int base = ((rt * 2 + kb) * 64 + lane) * 8;   // contiguous 16B/lane
            ah0[kb] = *(const short8*)&H0h[base];
            al0[kb] = *(const short8*)&H0l[base];
            ah1[kb] = *(const short8*)&H1h[base];
            al1[kb] = *(const short8*)&H1l[base];
        }
        int rowb = rt * 16 + quad * 4;
        float gr0[4], gr1[4];
        int tk[4];
#pragma unroll
        for (int r = 0; r < 4; ++r) {
            int row = rowb + r;
            bool ok = row < m;
            gr0[r] = ok ? bg0p[row] : 0.f;
            gr1[r] = ok ? (1.f - gr0[r]) : 0.f;
            tk[r]  = ok ? btokp[row] : 0;
        }
#pragma unroll
        for (int ci = 0; ci < 4; ++ci) {
            int ct = wv * 4 + ci;
            const unsigned short* p0h = w2ph + (((size_t)e0 * 16 + ct) * 2) * 512;
            const unsigned short* p0l = w2pl + (((size_t)e0 * 16 + ct) * 2) * 512;
            const unsigned short* p1h = w2ph + (((size_t)e1 * 16 + ct) * 2) * 512;
            const unsigned short* p1l = w2pl + (((size_t)e1 * 16 + ct) * 2) * 512;
            f32x4 acc = (f32x4){0, 0, 0, 0};
#pragma unroll
            for (int kb = 0; kb < 2; ++kb) {
                short8 bh = *(const short8*)(p0h + kb * 512 + lane * 8);
                short8 bl = *(const short8*)(p0l + kb * 512 + lane * 8);
                acc = __builtin_amdgcn_mfma_f32_16x16x32_bf16(ah0[kb], bh, acc, 0, 0, 0);
                acc = __builtin_amdgcn_mfma_f32_16x16x32_bf16(ah0[kb], bl, acc, 0, 0, 0);
                acc = __builtin_amdgcn_mfma_f32_16x16x32_bf16(al0[kb], bh, acc, 0, 0, 0);
                short8 ch = *(const short8*)(p1h + kb * 512 + lane * 8);
                short8 cl = *(const short8*)(p1l + kb * 512 + lane * 8);
                acc = __builtin_amdgcn_mfma_f32_16x16x32_bf16(ah1[kb], ch, acc, 0, 0, 0);
                acc = __builtin_amdgcn_mfma_f32_16x16x32_bf16(ah1[kb], cl, acc, 0, 0, 0);
                acc = __builtin_amdgcn_mfma_f32_16x16x32_bf16(al1[kb], ch, acc, 0, 0, 0);
            }
#pragma unroll
            for (int r = 0; r < 4; ++r) {
                int row = rowb + r;
                float val = acc[r] + gr0[r] * b20[ci] + gr1[r] * b21[ci];  // unscaled y
                if (row < m) {
                    kdacc += fabsf(val);
                    out[(size_t)tk[r] * EMBED + ct * 16 + ln15] = 0.5f * val;
                }
            }
        }
    }
    // KD reduction: wave-level shuffle + one atomic per wave (no LDS, no barrier)
#pragma unroll
    for (int o = 32; o > 0; o >>= 1) kdacc += __shfl_down(kdacc, o, 64);
    if (lane == 0) atomicAdd(&kdpart[bid & 63], kdacc);
}

// ---------------- Kernel 4: aux CV loss + kd loss (parallel loads; exact-int float sums) --------
__global__ __launch_bounds__(128) void loss_kernel(const int* __restrict__ pcount,
                            const float* __restrict__ importance,
                            const float* __restrict__ kdpart, float* __restrict__ loss_out)
{
    __shared__ float sload[NE];
    __shared__ float simp[NE];
    __shared__ float skd;
    int tid = threadIdx.x;
    if (tid < NE) { sload[tid] = 0.f; simp[tid] = importance[tid]; }
    __syncthreads();
    if (tid < 64) {
        float kd = kdpart[tid];
#pragma unroll
        for (int o = 32; o > 0; o >>= 1) kd += __shfl_down(kd, o, 64);
        if (tid == 0) skd = kd;
    }
    if (tid < NPAIR) {
        float c = (float)pcount[tid];                    // integer-valued: atomic order exact
        atomicAdd(&sload[tid / NE], c);
        atomicAdd(&sload[tid % NE], c);
    }
    __syncthreads();
    if (tid == 0) {
        float kd = skd * (1.f / (float)((size_t)T_TOKENS * EMBED));
        float mi = 0.f, ml = 0.f;
        for (int e = 0; e < NE; e++) { mi += simp[e]; ml += sload[e]; }
        mi *= (1.f / NE); ml *= (1.f / NE);
        float vi = 0.f, vl = 0.f;
        for (int e = 0; e < NE; e++) {
            float di = simp[e] - mi; vi += di * di;
            float dl = sload[e] - ml; vl += dl * dl;
        }
        vi *= (1.f / (NE - 1)); vl *= (1.f / (NE - 1));   // ddof=1
        float aux = vi / (mi * mi + 1e-10f) + vl / (ml * ml + 1e-10f);
        loss_out[0] = aux + kd;
    }
}

extern "C" void kernel_launch(void* const* d_in, const int* in_sizes, int n_in,
                              void* d_out, int out_size, void* d_ws, size_t ws_size,
                              hipStream_t stream)
{
    (void)in_sizes; (void)n_in; (void)out_size; (void)ws_size;
    const float* x  = (const float*)d_in[0];
    const float* wg = (const float*)d_in[1];
    const float* w1 = (const float*)d_in[2];
    const float* b1 = (const float*)d_in[3];
    const float* w2 = (const float*)d_in[4];
    const float* b2 = (const float*)d_in[5];
    float* out = (float*)d_out;

    char* ws = (char*)d_ws;
    int*   pcount     = (int*)ws;                  // 128 ints (100 used)
    float* importance = (float*)(ws + 512);        // 16 floats
    float* kdpart     = (float*)(ws + 576);        // 64 floats
    int*   nq         = (int*)(ws + 832);
    int*   qp         = (int*)(ws + 1024);         // MAXQ ints
    int*   qs         = (int*)(ws + 1024 + MAXQ * 4);
    size_t off = 16384;
    int*   btok = (int*)(ws + off);    off += (size_t)NPAIR * T_TOKENS * 4;   // 26.2 MB
    float* bg0  = (float*)(ws + off);  off += (size_t)NPAIR * T_TOKENS * 4;   // 26.2 MB
    unsigned short* w1ph = (unsigned short*)(ws + off); off += 327680;
    unsigned short* w1pl = (unsigned short*)(ws + off); off += 327680;
    unsigned short* w2ph = (unsigned short*)(ws + off); off += 327680;
    unsigned short* w2pl = (unsigned short*)(ws + off); off += 327680;      // ~53.8 MB total

    hipMemsetAsync(ws, 0, 1024, stream);   // pcount + importance + kdpart + nq

    gate_pack_kernel<<<NGATE + NPACK, 256, 0, stream>>>(
        x, wg, w1, w2, w1ph, w1pl, w2ph, w2pl, pcount, importance, btok, bg0);
    queue_kernel<<<1, 128, 0, stream>>>(pcount, qp, qs, nq);
    expert_kernel<<<NEXP, 256, 0, stream>>>(
        x, w1ph, w1pl, w2ph, w2pl, b1, b2, pcount, qp, qs, nq, btok, bg0, out, kdpart);
    loss_kernel<<<1, 128, 0, stream>>>(pcount, importance, kdpart, out + (size_t)T_TOKENS * EMBED);
}

// Round 7
// 214.988 us; speedup vs baseline: 1.1006x; 1.1006x over previous
//
#include <hip/hip_runtime.h>
#include <hip/hip_bf16.h>

#define T_TOKENS 65536
#define EMBED 256
#define DOWN 64
#define NE 10
#define NPAIR 100          // ordered (e0,e1) buckets, e0=top1
#define MAXQ 1280          // >= 1024 + 99 tiles worst case
#define NGATE 256          // gating blocks (T_TOKENS/256)
#define NPACK 160          // pack role blocks
#define NEXP 1123          // expert grid: worst-case tiles 1024 + 99

typedef __attribute__((ext_vector_type(8))) short short8;   // 8 bf16 (MFMA A/B frag)
typedef __attribute__((ext_vector_type(4))) float f32x4;    // MFMA C/D frag

__device__ inline unsigned short f2bf(float f) {            // RNE float->bf16
    unsigned u = __builtin_bit_cast(unsigned, f);
    u += 0x7fff + ((u >> 16) & 1);
    return (unsigned short)(u >> 16);
}
__device__ inline float bf2f(unsigned short h) {
    unsigned u = ((unsigned)h) << 16;
    return __builtin_bit_cast(float, u);
}

// ---------------- Kernel 1 (fused, fence-free): gating blocks [0,256) + pack blocks [256,416) ----
// Roles independent; kernel boundary before expert provides ordering. No fences/counters
// (round-4 lesson: device fence per block -> per-block L2 writeback -> +117us).
// Gating FMA order IDENTICAL to prior rounds -- do not reorder: near-tie top-k.
__global__ __launch_bounds__(256) void gate_pack_kernel(
    const float* __restrict__ x, const float* __restrict__ wg,
    const float* __restrict__ w1, const float* __restrict__ w2,
    unsigned short* __restrict__ w1ph, unsigned short* __restrict__ w1pl,
    unsigned short* __restrict__ w2ph, unsigned short* __restrict__ w2pl,
    int* __restrict__ pcount, float* __restrict__ importance,
    int* __restrict__ btok, float* __restrict__ bg0)
{
    int tid = threadIdx.x;

    if (blockIdx.x >= NGATE) {                 // ---- pack role ----
        int gid = (blockIdx.x - NGATE) * 256 + tid;
        int lane = gid & 63;
        int fid = gid >> 6;
        int n16 = lane & 15;
        int kbase = ((lane >> 4) & 3) * 8;
        if (fid < 320) {            // w1: fid = (e*4 + ct)*8 + kb
            int kb = fid & 7, ect = fid >> 3;
            int ct = ect & 3, e = ect >> 2;
            int n = ct * 16 + n16;
            int k0 = kb * 32 + kbase;
#pragma unroll
            for (int j = 0; j < 8; ++j) {
                float v = w1[((size_t)e * EMBED + k0 + j) * DOWN + n];
                unsigned short h = f2bf(v);
                w1ph[(size_t)fid * 512 + lane * 8 + j] = h;
                w1pl[(size_t)fid * 512 + lane * 8 + j] = f2bf(v - bf2f(h));
            }
        } else if (fid < 640) {     // w2: f2 = (e*16 + ct)*2 + kb
            int f2 = fid - 320;
            int kb = f2 & 1, ect = f2 >> 1;
            int ct = ect & 15, e = ect >> 4;
            int n = ct * 16 + n16;
            int k0 = kb * 32 + kbase;
#pragma unroll
            for (int j = 0; j < 8; ++j) {
                float v = w2[((size_t)e * DOWN + k0 + j) * EMBED + n];
                unsigned short h = f2bf(v);
                w2ph[(size_t)f2 * 512 + lane * 8 + j] = h;
                w2pl[(size_t)f2 * 512 + lane * 8 + j] = f2bf(v - bf2f(h));
            }
        }
        return;
    }

    // ---- gating role (body identical to round-3/5) ----
    __shared__ float Xs[2][256 * 33];    // stride 33: compute reads (tid+c)%32 conflict-free
    __shared__ int lcount[NPAIR];
    __shared__ int gbase[NPAIR];
    __shared__ float limp[16];
    if (tid < NPAIR) lcount[tid] = 0;
    if (tid < 16) limp[tid] = 0.f;

    int tokbase = blockIdx.x * 256;
    const float4* x4 = (const float4*)x;
    int rbase = tid >> 3, c4 = tid & 7;   // 8 rows x 8 float4: 128B segments per row

    float4 pre0[8], pre1[8];
#pragma unroll
    for (int i = 0; i < 8; ++i)
        pre0[i] = x4[(size_t)(tokbase + i * 32 + rbase) * 64 + c4];
#pragma unroll
    for (int i = 0; i < 8; ++i)
        pre1[i] = x4[(size_t)(tokbase + i * 32 + rbase) * 64 + 8 + c4];

    float acc[NE];
#pragma unroll
    for (int e = 0; e < NE; e++) acc[e] = 0.f;

    for (int cp = 0; cp < 4; ++cp) {
        {   // even chunk cc = 2*cp -> buffer 0, regs pre0
            float* buf = Xs[0];
#pragma unroll
            for (int i = 0; i < 8; ++i) {
                float* d = &buf[(i * 32 + rbase) * 33 + c4 * 4];
                d[0] = pre0[i].x; d[1] = pre0[i].y; d[2] = pre0[i].z; d[3] = pre0[i].w;
            }
            if (cp < 3) {
#pragma unroll
                for (int i = 0; i < 8; ++i)
                    pre0[i] = x4[(size_t)(tokbase + i * 32 + rbase) * 64 + (2 * cp + 2) * 8 + c4];
            }
            __syncthreads();   // single barrier/chunk: buffer alternation protects reuse
            const float* wgc = wg + (2 * cp) * 32 * NE;   // wave-uniform -> scalar loads
#pragma unroll
            for (int c = 0; c < 32; ++c) {
                float xv = buf[tid * 33 + c];
#pragma unroll
                for (int e = 0; e < NE; ++e)
                    acc[e] = fmaf(xv, wgc[c * NE + e], acc[e]);
            }
        }
        {   // odd chunk cc = 2*cp+1 -> buffer 1, regs pre1
            float* buf = Xs[1];
#pragma unroll
            for (int i = 0; i < 8; ++i) {
                float* d = &buf[(i * 32 + rbase) * 33 + c4 * 4];
                d[0] = pre1[i].x; d[1] = pre1[i].y; d[2] = pre1[i].z; d[3] = pre1[i].w;
            }
            if (cp < 3) {
#pragma unroll
                for (int i = 0; i < 8; ++i)
                    pre1[i] = x4[(size_t)(tokbase + i * 32 + rbase) * 64 + (2 * cp + 3) * 8 + c4];
            }
            __syncthreads();
            const float* wgc = wg + (2 * cp + 1) * 32 * NE;
#pragma unroll
            for (int c = 0; c < 32; ++c) {
                float xv = buf[tid * 33 + c];
#pragma unroll
                for (int e = 0; e < NE; ++e)
                    acc[e] = fmaf(xv, wgc[c * NE + e], acc[e]);
            }
        }
    }

    // top-2 (first occurrence wins ties, matches lax.top_k)
    float l0 = -INFINITY, l1 = -INFINITY;
    int i0 = 0, i1 = 0;
#pragma unroll
    for (int e = 0; e < NE; e++) {
        float v = acc[e];
        if (v > l0) { l1 = l0; i1 = i0; l0 = v; i0 = e; }
        else if (v > l1) { l1 = v; i1 = e; }
    }
    float ex = __expf(l1 - l0);
    float g0 = 1.f / (1.f + ex);

    int p = i0 * NE + i1;
    int lp = atomicAdd(&lcount[p], 1);
    atomicAdd(&limp[i0], g0);
    atomicAdd(&limp[i1], 1.f - g0);
    __syncthreads();
    if (tid < NPAIR) {
        int c = lcount[tid];
        gbase[tid] = c ? atomicAdd(&pcount[tid], c) : 0;
    }
    if (tid < NE) atomicAdd(&importance[tid], limp[tid]);
    __syncthreads();
    int pos = gbase[p] + lp;
    btok[p * T_TOKENS + pos] = tokbase + tid;
    bg0[p * T_TOKENS + pos] = g0;
}

// ---------------- Kernel 2: build tile work-queue (parallel scan) -------------------------------
__global__ __launch_bounds__(128) void queue_kernel(const int* __restrict__ pcount,
                             int* __restrict__ qp, int* __restrict__ qs, int* __restrict__ nq)
{
    __shared__ int sc[2][128];
    int tid = threadIdx.x;
    int c = (tid < NPAIR) ? pcount[tid] : 0;
    int t = (c + 63) >> 6;
    sc[0][tid] = t;
    __syncthreads();
    int cur = 0;
#pragma unroll
    for (int o = 1; o < 128; o <<= 1) {    // Hillis-Steele inclusive scan
        int v = sc[cur][tid] + ((tid >= o) ? sc[cur][tid - o] : 0);
        sc[cur ^ 1][tid] = v;
        __syncthreads();
        cur ^= 1;
    }
    int incl = sc[cur][tid];
    int excl = incl - t;
    if (tid == 127) *nq = incl;            // tids >= NPAIR contribute 0
    for (int i = 0; i < t; ++i) { qp[excl + i] = tid; qs[excl + i] = i * 64; }
}

// ---------------- Kernel 3: fused pair-FFN -------------------------------------------------------
// Round-7: async global->LDS x staging (spill-free prefetch). Theory: the chunk loop's
// [load -> convert -> barrier -> MFMA] left zero x-loads in flight during the MFMA phase ->
// ~50% memory duty cycle -> 2.5 TB/s. Now chunk cc+1's raw f32 tile is staged into a 16 KB LDS
// region via global_load_lds (width 16) DURING chunk cc's MFMA phase. Prefetch buffer is LDS,
// not VGPRs -> no register-liveness spill (round-2's failure mode impossible).
// LDS: Xh/Xl (16 KB, XOR-swizzled, round-6-proven) + Xf32 (16 KB) = 32 KB Hbuf; H overlays all.
// toks/gv/kdw back in dedicated LDS (round-6's global re-reads cost +9MB HBM -> reverted).
__global__ __launch_bounds__(256, 3) void expert_kernel(
    const float* __restrict__ x,
    const unsigned short* __restrict__ w1ph, const unsigned short* __restrict__ w1pl,
    const unsigned short* __restrict__ w2ph, const unsigned short* __restrict__ w2pl,
    const float* __restrict__ b1, const float* __restrict__ b2,
    const int* __restrict__ pcount, const int* __restrict__ qp, const int* __restrict__ qs,
    const int* __restrict__ nq,
    const int* __restrict__ btok, const float* __restrict__ bg0,
    float* __restrict__ out, float* __restrict__ kdpart)
{
    int bid = blockIdx.x;
    if (bid >= *nq) return;
    int p = qp[bid], s = qs[bid];
    int e0 = p / NE, e1 = p - e0 * NE;
    int m = min(64, pcount[p] - s);

    __shared__ __align__(16) unsigned short Hbuf[16384];   // 32 KB
    __shared__ int toks[64];
    __shared__ float gv0s[64], gv1s[64];
    __shared__ float kdw[4];

    // GEMM1 overlay: Xh/Xl swizzled bf16 [0,16K); Xf32 raw staging [16K,32K)
    unsigned short* const Xh = Hbuf;                 // 4096 shorts
    unsigned short* const Xl = Hbuf + 4096;          // 4096 shorts
    float* const Xf          = (float*)(Hbuf + 8192); // 4096 floats (16 KB)
    // GEMM2 overlay (after X/Xf dead):
    unsigned short* const H0h = Hbuf;
    unsigned short* const H0l = Hbuf + 4096;
    unsigned short* const H1h = Hbuf + 8192;
    unsigned short* const H1l = Hbuf + 12288;

    int tid = threadIdx.x;
    if (tid < 64) {
        int v = 0; float g = 0.f;
        if (tid < m) {
            v = btok[p * T_TOKENS + s + tid];
            g = bg0[p * T_TOKENS + s + tid];
        }
        toks[tid] = v;
        gv0s[tid] = g;
        gv1s[tid] = (tid < m) ? (1.f - g) : 0.f;
    }
    __syncthreads();

    int lane = tid & 63, wv = tid >> 6;
    int ln15 = lane & 15, quad = lane >> 4;
    int srow = tid >> 2, sc0 = (tid & 3) * 16;
    bool srow_ok = srow < m;
    const float* xrow = x + (size_t)toks[srow] * EMBED;   // srow>=m -> token 0 (zeroed at convert)

    f32x4 a10[4], a11[4];
#pragma unroll
    for (int rt = 0; rt < 4; ++rt) { a10[rt] = (f32x4){0,0,0,0}; a11[rt] = (f32x4){0,0,0,0}; }

    const unsigned short* w1h0 = w1ph + (((size_t)e0 * 4 + wv) * 8) * 512;
    const unsigned short* w1l0 = w1pl + (((size_t)e0 * 4 + wv) * 8) * 512;
    const unsigned short* w1h1 = w1ph + (((size_t)e1 * 4 + wv) * 8) * 512;
    const unsigned short* w1l1 = w1pl + (((size_t)e1 * 4 + wv) * 8) * 512;

    // prologue: async-stage chunk 0 into Xf (16B/lane, LDS dest linear in lane order)
#pragma unroll
    for (int p4 = 0; p4 < 4; ++p4) {
        const float* g = xrow + sc0 + p4 * 4;
        float* l = &Xf[((p4 * 4 + wv) * 64 + lane) * 4];
        __builtin_amdgcn_global_load_lds(
            (const __attribute__((address_space(1))) void*)g,
            (__attribute__((address_space(3))) void*)l, 16, 0, 0);
    }

    for (int cc = 0; cc < 4; ++cc) {                 // K chunks of 64
        __syncthreads();   // drains vmcnt: Xf[cc] ready; prev chunk's Xh/Xl reads done
        // convert Xf -> Xh/Xl (swizzled); zero rows >= m
#pragma unroll
        for (int p4 = 0; p4 < 4; ++p4) {
            float4 v = *(const float4*)&Xf[((p4 * 4 + wv) * 64 + lane) * 4];
            if (!srow_ok) v = make_float4(0.f, 0.f, 0.f, 0.f);
            const float* vs = (const float*)&v;
            ushort4 hv, lv;
            unsigned short* hp = (unsigned short*)&hv;
            unsigned short* lp2 = (unsigned short*)&lv;
#pragma unroll
            for (int i = 0; i < 4; ++i) {
                unsigned short h = f2bf(vs[i]);
                hp[i] = h;
                lp2[i] = f2bf(vs[i] - bf2f(h));
            }
            int col = sc0 + p4 * 4;
            int sidx = (srow * 64 + col) ^ ((srow & 7) << 3);   // 16B-slot XOR swizzle
            *(ushort4*)&Xh[sidx] = hv;
            *(ushort4*)&Xl[sidx] = lv;
        }
        __syncthreads();   // Xh/Xl published; Xf free for next chunk
        if (cc < 3) {      // issue next chunk's async loads: they fly under the MFMA phase below
#pragma unroll
            for (int p4 = 0; p4 < 4; ++p4) {
                const float* g = xrow + (cc + 1) * 64 + sc0 + p4 * 4;
                float* l = &Xf[((p4 * 4 + wv) * 64 + lane) * 4];
                __builtin_amdgcn_global_load_lds(
                    (const __attribute__((address_space(1))) void*)g,
                    (__attribute__((address_space(3))) void*)l, 16, 0, 0);
            }
        }
#pragma unroll
        for (int kb = 0; kb < 2; ++kb) {
            int kbg = cc * 2 + kb;
            short8 bh0 = *(const short8*)(w1h0 + (size_t)kbg * 512 + lane * 8);
            short8 bl0 = *(const short8*)(w1l0 + (size_t)kbg * 512 + lane * 8);
            short8 bh1 = *(const short8*)(w1h1 + (size_t)kbg * 512 + lane * 8);
            short8 bl1 = *(const short8*)(w1l1 + (size_t)kbg * 512 + lane * 8);
            int aoff = kb * 32 + quad * 8;
#pragma unroll
            for (int rt = 0; rt < 4; ++rt) {
                int row = rt * 16 + ln15;
                int aidx = (row * 64 + aoff) ^ ((row & 7) << 3);
                short8 ah = *(const short8*)&Xh[aidx];
                short8 al = *(const short8*)&Xl[aidx];
                a10[rt] = __builtin_amdgcn_mfma_f32_16x16x32_bf16(ah, bh0, a10[rt], 0, 0, 0);
                a10[rt] = __builtin_amdgcn_mfma_f32_16x16x32_bf16(ah, bl0, a10[rt], 0, 0, 0);
                a10[rt] = __builtin_amdgcn_mfma_f32_16x16x32_bf16(al, bh0, a10[rt], 0, 0, 0);
                a11[rt] = __builtin_amdgcn_mfma_f32_16x16x32_bf16(ah, bh1, a11[rt], 0, 0, 0);
                a11[rt] = __builtin_amdgcn_mfma_f32_16x16x32_bf16(ah, bl1, a11[rt], 0, 0, 0);
                a11[rt] = __builtin_amdgcn_mfma_f32_16x16x32_bf16(al, bh1, a11[rt], 0, 0, 0);
            }
        }
        // no barrier here: next iteration's top-of-loop barrier orders Xh/Xl reuse
    }
    __syncthreads();   // all GEMM1 LDS reads done; Hbuf reusable as H

    // H epilogue: bias+relu, pre-scale by gates, write in A-frag order
    {
        float b1v0 = b1[e0 * DOWN + wv * 16 + ln15];
        float b1v1 = b1[e1 * DOWN + wv * 16 + ln15];
        int kbH = wv >> 1;
        int laneH = (((wv & 1) * 2 + (ln15 >> 3)) * 16) + quad * 4;
        int jH = ln15 & 7;
#pragma unroll
        for (int rt = 0; rt < 4; ++rt) {
#pragma unroll
            for (int r = 0; r < 4; ++r) {
                int row = rt * 16 + quad * 4 + r;
                float g0 = gv0s[row], g1 = gv1s[row];
                float h0 = fmaxf(a10[rt][r] + b1v0, 0.f) * g0;
                float h1 = fmaxf(a11[rt][r] + b1v1, 0.f) * g1;
                int idx = ((rt * 2 + kbH) * 64 + laneH + r) * 8 + jH;
                unsigned short h0h = f2bf(h0);
                unsigned short h1h = f2bf(h1);
                H0h[idx] = h0h; H0l[idx] = f2bf(h0 - bf2f(h0h));
                H1h[idx] = h1h; H1l[idx] = f2bf(h1 - bf2f(h1h));
            }
        }
    }
    __syncthreads();

    // GEMM2: y = (g0 h0) w2_e0 + (g1 h1) w2_e1; epilogue adds gated biases, KD, 0.5 scale
    float b20[4], b21[4];
#pragma unroll
    for (int ci = 0; ci < 4; ++ci) {
        b20[ci] = b2[e0 * EMBED + (wv * 4 + ci) * 16 + ln15];
        b21[ci] = b2[e1 * EMBED + (wv * 4 + ci) * 16 + ln15];
    }
    float kdacc = 0.f;
#pragma unroll
    for (int rt = 0; rt < 4; ++rt) {
        short8 ah0[2], al0[2], ah1[2], al1[2];
#pragma unroll
        for (int kb = 0; kb < 2; ++kb) {
            int base = ((rt * 2 + kb) * 64 + lane) * 8;   // contiguous 16B/lane
            ah0[kb] = *(const short8*)&H0h[base];
            al0[kb] = *(const short8*)&H0l[base];
            ah1[kb] = *(const short8*)&H1h[base];
            al1[kb] = *(const short8*)&H1l[base];
        }
        int rowb = rt * 16 + quad * 4;
        float gr0[4], gr1[4];
#pragma unroll
        for (int r = 0; r < 4; ++r) { gr0[r] = gv0s[rowb + r]; gr1[r] = gv1s[rowb + r]; }
#pragma unroll
        for (int ci = 0; ci < 4; ++ci) {
            int ct = wv * 4 + ci;
            const unsigned short* p0h = w2ph + (((size_t)e0 * 16 + ct) * 2) * 512;
            const unsigned short* p0l = w2pl + (((size_t)e0 * 16 + ct) * 2) * 512;
            const unsigned short* p1h = w2ph + (((size_t)e1 * 16 + ct) * 2) * 512;
            const unsigned short* p1l = w2pl + (((size_t)e1 * 16 + ct) * 2) * 512;
            f32x4 acc = (f32x4){0, 0, 0, 0};
#pragma unroll
            for (int kb = 0; kb < 2; ++kb) {
                short8 bh = *(const short8*)(p0h + kb * 512 + lane * 8);
                short8 bl = *(const short8*)(p0l + kb * 512 + lane * 8);
                acc = __builtin_amdgcn_mfma_f32_16x16x32_bf16(ah0[kb], bh, acc, 0, 0, 0);
                acc = __builtin_amdgcn_mfma_f32_16x16x32_bf16(ah0[kb], bl, acc, 0, 0, 0);
                acc = __builtin_amdgcn_mfma_f32_16x16x32_bf16(al0[kb], bh, acc, 0, 0, 0);
                short8 ch = *(const short8*)(p1h + kb * 512 + lane * 8);
                short8 cl = *(const short8*)(p1l + kb * 512 + lane * 8);
                acc = __builtin_amdgcn_mfma_f32_16x16x32_bf16(ah1[kb], ch, acc, 0, 0, 0);
                acc = __builtin_amdgcn_mfma_f32_16x16x32_bf16(ah1[kb], cl, acc, 0, 0, 0);
                acc = __builtin_amdgcn_mfma_f32_16x16x32_bf16(al1[kb], ch, acc, 0, 0, 0);
            }
#pragma unroll
            for (int r = 0; r < 4; ++r) {
                int row = rowb + r;
                float val = acc[r] + gr0[r] * b20[ci] + gr1[r] * b21[ci];  // unscaled y
                if (row < m) {
                    kdacc += fabsf(val);
                    out[(size_t)toks[row] * EMBED + ct * 16 + ln15] = 0.5f * val;
                }
            }
        }
    }
    // KD block reduction
#pragma unroll
    for (int o = 32; o > 0; o >>= 1) kdacc += __shfl_down(kdacc, o, 64);
    if (lane == 0) kdw[wv] = kdacc;
    __syncthreads();
    if (tid == 0)
        atomicAdd(&kdpart[bid & 63], kdw[0] + kdw[1] + kdw[2] + kdw[3]);
}

// ---------------- Kernel 4: aux CV loss + kd loss (parallel loads; exact-int float sums) --------
__global__ __launch_bounds__(128) void loss_kernel(const int* __restrict__ pcount,
                            const float* __restrict__ importance,
                            const float* __restrict__ kdpart, float* __restrict__ loss_out)
{
    __shared__ float sload[NE];
    __shared__ float simp[NE];
    __shared__ float skd;
    int tid = threadIdx.x;
    if (tid < NE) { sload[tid] = 0.f; simp[tid] = importance[tid]; }
    __syncthreads();
    if (tid < 64) {
        float kd = kdpart[tid];
#pragma unroll
        for (int o = 32; o > 0; o >>= 1) kd += __shfl_down(kd, o, 64);
        if (tid == 0) skd = kd;
    }
    if (tid < NPAIR) {
        float c = (float)pcount[tid];                    // integer-valued: atomic order exact
        atomicAdd(&sload[tid / NE], c);
        atomicAdd(&sload[tid % NE], c);
    }
    __syncthreads();
    if (tid == 0) {
        float kd = skd * (1.f / (float)((size_t)T_TOKENS * EMBED));
        float mi = 0.f, ml = 0.f;
        for (int e = 0; e < NE; e++) { mi += simp[e]; ml += sload[e]; }
        mi *= (1.f / NE); ml *= (1.f / NE);
        float vi = 0.f, vl = 0.f;
        for (int e = 0; e < NE; e++) {
            float di = simp[e] - mi; vi += di * di;
            float dl = sload[e] - ml; vl += dl * dl;
        }
        vi *= (1.f / (NE - 1)); vl *= (1.f / (NE - 1));   // ddof=1
        float aux = vi / (mi * mi + 1e-10f) + vl / (ml * ml + 1e-10f);
        loss_out[0] = aux + kd;
    }
}

extern "C" void kernel_launch(void* const* d_in, const int* in_sizes, int n_in,
                              void* d_out, int out_size, void* d_ws, size_t ws_size,
                              hipStream_t stream)
{
    (void)in_sizes; (void)n_in; (void)out_size; (void)ws_size;
    const float* x  = (const float*)d_in[0];
    const float* wg = (const float*)d_in[1];
    const float* w1 = (const float*)d_in[2];
    const float* b1 = (const float*)d_in[3];
    const float* w2 = (const float*)d_in[4];
    const float* b2 = (const float*)d_in[5];
    float* out = (float*)d_out;

    char* ws = (char*)d_ws;
    int*   pcount     = (int*)ws;                  // 128 ints (100 used)
    float* importance = (float*)(ws + 512);        // 16 floats
    float* kdpart     = (float*)(ws + 576);        // 64 floats
    int*   nq         = (int*)(ws + 832);
    int*   qp         = (int*)(ws + 1024);         // MAXQ ints
    int*   qs         = (int*)(ws + 1024 + MAXQ * 4);
    size_t off = 16384;
    int*   btok = (int*)(ws + off);    off += (size_t)NPAIR * T_TOKENS * 4;   // 26.2 MB
    float* bg0  = (float*)(ws + off);  off += (size_t)NPAIR * T_TOKENS * 4;   // 26.2 MB
    unsigned short* w1ph = (unsigned short*)(ws + off); off += 327680;
    unsigned short* w1pl = (unsigned short*)(ws + off); off += 327680;
    unsigned short* w2ph = (unsigned short*)(ws + off); off += 327680;
    unsigned short* w2pl = (unsigned short*)(ws + off); off += 327680;      // ~53.8 MB total

    hipMemsetAsync(ws, 0, 1024, stream);   // pcount + importance + kdpart + nq

    gate_pack_kernel<<<NGATE + NPACK, 256, 0, stream>>>(
        x, wg, w1, w2, w1ph, w1pl, w2ph, w2pl, pcount, importance, btok, bg0);
    queue_kernel<<<1, 128, 0, stream>>>(pcount, qp, qs, nq);
    expert_kernel<<<NEXP, 256, 0, stream>>>(
        x, w1ph, w1pl, w2ph, w2pl, b1, b2, pcount, qp, qs, nq, btok, bg0, out, kdpart);
    loss_kernel<<<1, 128, 0, stream>>>(pcount, importance, kdpart, out + (size_t)T_TOKENS * EMBED);
}